// Round 7
// baseline (380.216 us; speedup 1.0000x reference)
//
#include <hip/hip_runtime.h>
#include <math.h>

#define IMG 56
#define HW 3136          // 56*56
#define NCH 256
#define NB 32
#define SAMPLE (NCH*HW)  // 802816
#define TOT (NB*SAMPLE)  // 25690112
#define ASTR 68          // As row stride in dwords (16B-aligned, granule-uniform)

typedef int i32x4 __attribute__((ext_vector_type(4)));

// ---------- helpers ----------

__device__ __forceinline__ float qz(float x, float mn, float scale) {
    float t = (x - mn) / scale;
    t = fminf(fmaxf(t, 0.f), 255.f);
    return rintf(t) * scale + mn;   // rintf = round-half-even, matches jnp.round
}

__device__ __forceinline__ float codef(float x, float mn, float scale) {
    return rintf(fminf(fmaxf((x - mn) / scale, 0.f), 255.f));   // integer code 0..255
}

// order-preserving float<->uint encode for atomicMin/Max on floats
__device__ __forceinline__ unsigned enc(float f) {
    unsigned u = __float_as_uint(f);
    return (u & 0x80000000u) ? ~u : (u ^ 0x80000000u);
}
__device__ __forceinline__ float dec(unsigned u) {
    unsigned v = (u & 0x80000000u) ? (u ^ 0x80000000u) : ~u;
    return __uint_as_float(v);
}

// block-level min/max reduce (result valid on thread 0). blockDim must be mult of 64.
__device__ __forceinline__ void blk_red_minmax(float& mn, float& mx) {
    __shared__ float smn[4], smx[4];
    __syncthreads();
    #pragma unroll
    for (int o = 32; o > 0; o >>= 1) {
        mn = fminf(mn, __shfl_down(mn, o));
        mx = fmaxf(mx, __shfl_down(mx, o));
    }
    int lane = threadIdx.x & 63, w = threadIdx.x >> 6;
    if (lane == 0) { smn[w] = mn; smx[w] = mx; }
    __syncthreads();
    if (threadIdx.x == 0) {
        int nw = (int)blockDim.x >> 6;
        for (int i = 1; i < nw; i++) { mn = fminf(mn, smn[i]); mx = fmaxf(mx, smx[i]); }
    }
}

__device__ __forceinline__ void blk_red_minmax_bcast(float& mn, float& mx) {
    __shared__ float bb[2];
    blk_red_minmax(mn, mx);
    if (threadIdx.x == 0) { bb[0] = mn; bb[1] = mx; }
    __syncthreads();
    mn = bb[0]; mx = bb[1];
}

__device__ __forceinline__ float blk_red_sum(float v) {
    __shared__ float ss[4];
    __syncthreads();
    #pragma unroll
    for (int o = 32; o > 0; o >>= 1) v += __shfl_down(v, o);
    int lane = threadIdx.x & 63, w = threadIdx.x >> 6;
    if (lane == 0) ss[w] = v;
    __syncthreads();
    if (threadIdx.x == 0) {
        int nw = (int)blockDim.x >> 6;
        for (int i = 1; i < nw; i++) v += ss[i];
    }
    return v;
}

// ---------- kernels ----------

__global__ void k_init(unsigned* xsl, unsigned* pwsl, unsigned* o2mn, unsigned* o2mx, float* o2sum) {
    int i = blockIdx.x * 256 + threadIdx.x;   // grid 32 -> 8192
    o2mn[i] = 0xFFFFFFFFu; o2mx[i] = 0u; o2sum[i] = 0.f;
    if (blockIdx.x == 0) {
        if (threadIdx.x < 64) xsl[threadIdx.x] = (threadIdx.x < 32) ? 0xFFFFFFFFu : 0u;
        if (threadIdx.x == 64) { pwsl[0] = 0xFFFFFFFFu; pwsl[1] = 0u; }
    }
}

// merged front: blocks 0..511 per-sample min/max of x; blocks 512..575 pw min/max
__global__ __launch_bounds__(256) void k_front(const float4* __restrict__ x4, const float4* __restrict__ pw4,
                                               unsigned* xsl, unsigned* pwsl) {
    int id = blockIdx.x;
    if (id < 512) {
        int b = id >> 4, blk = id & 15;
        const float4* p = x4 + (size_t)b * 200704 + (size_t)blk * 12544;
        float mn = INFINITY, mx = -INFINITY;
        for (int k = threadIdx.x; k < 12544; k += 256) {
            float4 v = p[k];
            mn = fminf(mn, fminf(fminf(v.x, v.y), fminf(v.z, v.w)));
            mx = fmaxf(mx, fmaxf(fmaxf(v.x, v.y), fmaxf(v.z, v.w)));
        }
        blk_red_minmax(mn, mx);
        if (threadIdx.x == 0) {
            atomicMin(&xsl[b], enc(mn));
            atomicMax(&xsl[32 + b], enc(mx));
        }
    } else {
        int i = (id - 512) * 256 + threadIdx.x;
        float4 v = pw4[i];
        float mn = fminf(fminf(v.x, v.y), fminf(v.z, v.w));
        float mx = fmaxf(fmaxf(v.x, v.y), fmaxf(v.z, v.w));
        blk_red_minmax(mn, mx);
        if (threadIdx.x == 0) { atomicMin(&pwsl[0], enc(mn)); atomicMax(&pwsl[1], enc(mx)); }
    }
}

// sc layout: 0 mn_x 1 s_x | 2 mn_w1 3 s_w1 | 4 mn_b1 5 s_b1 | 6 mn_h1 7 s_h1
//            8 mn_h2 9 s_h2 | 10 mn_w2 11 s_w2 | 12 mn_o2 13 s_o2 | 14 r1=1/s1 15 B1=-mn1/s1
__global__ void k_fin1(const float* __restrict__ dww, const float* __restrict__ dwb,
                       const unsigned* __restrict__ xsl, const unsigned* __restrict__ pwsl, float* sc) {
    int tid = threadIdx.x;
    float mn = INFINITY, mx = -INFINITY;
    #pragma unroll
    for (int i = 0; i < 9; i++) {
        int idx = i * 256 + tid;
        if (idx < 2304) { float v = dww[idx]; mn = fminf(mn, v); mx = fmaxf(mx, v); }
    }
    blk_red_minmax(mn, mx);
    float w1min = mn, w1max = mx;
    float v = dwb[tid]; mn = v; mx = v;
    blk_red_minmax(mn, mx);
    if (tid == 0) {
        float sm = 0.f, sx = 0.f;
        for (int i = 0; i < 32; i++) { sm += dec(xsl[i]); sx += dec(xsl[32 + i]); }
        float m = sm / 32.f, X = sx / 32.f;
        sc[0] = m;      sc[1] = fmaxf((X - m) / 255.f, 1e-8f);
        sc[2] = w1min;  sc[3] = fmaxf((w1max - w1min) / 255.f, 1e-8f);
        sc[4] = mn;     sc[5] = fmaxf((mx - mn) / 255.f, 1e-8f);
        float pmn = dec(pwsl[0]), pmx = dec(pwsl[1]);
        sc[10] = pmn; sc[11] = fmaxf((pmx - pmn) / 255.f, 1e-8f);
    }
}

// pw-weight offset codes (i8 = code-128, layout [co][ci]) + per-co raw code sums
__global__ __launch_bounds__(256) void k_qw(const float* __restrict__ pw, const float* __restrict__ sc,
                                            char* __restrict__ wcodes, float* __restrict__ Wsum) {
    int co = blockIdx.x, ci = threadIdx.x;
    float kw = codef(pw[co * 256 + ci], sc[10], sc[11]);
    wcodes[co * 256 + ci] = (char)((int)kw - 128);
    float s = blk_red_sum(kw);
    if (ci == 0) Wsum[co] = s;
}

// depthwise 3x3 pad=1; float4 staged LDS tile (stride 68, left pad 4), halo-only zeroing
__global__ __launch_bounds__(256) void k_dwconv(const float4* __restrict__ x4, const float* __restrict__ w,
                                                const float* __restrict__ bias, float* __restrict__ h1,
                                                const float* __restrict__ sc,
                                                float* __restrict__ h1mn, float* __restrict__ h1mx,
                                                float* __restrict__ h1sm) {
    int bc = blockIdx.x, c = bc & 255;
    __shared__ float tile[58 * 68];
    int tid = threadIdx.x;
    // zero only the halo ring: rows 0,57 cols 3..60; cols 3,60 rows 1..56 (228 cells)
    if (tid < 228) {
        int row, col2;
        if (tid < 58)       { row = 0;              col2 = 3 + tid; }
        else if (tid < 116) { row = 57;             col2 = 3 + tid - 58; }
        else if (tid < 172) { row = 1 + tid - 116;  col2 = 3; }
        else                { row = 1 + tid - 172;  col2 = 60; }
        tile[row * 68 + col2] = 0.f;
    }
    float mnx = sc[0], scx = sc[1];
    const float4* px = x4 + (size_t)bc * 784;
    #pragma unroll
    for (int it = 0; it < 4; it++) {
        int idx = it * 256 + tid;
        if (idx < 784) {
            int i = idx / 14, j = (idx - i * 14) * 4;
            float4 v = px[idx];
            v.x = qz(v.x, mnx, scx); v.y = qz(v.y, mnx, scx);
            v.z = qz(v.z, mnx, scx); v.w = qz(v.w, mnx, scx);
            *(float4*)&tile[(i + 1) * 68 + j + 4] = v;
        }
    }
    __syncthreads();
    float qw[9];
    #pragma unroll
    for (int k = 0; k < 9; k++) qw[k] = qz(w[c * 9 + k], sc[2], sc[3]);
    float qb = qz(bias[c], sc[4], sc[5]);
    float4* po = (float4*)(h1 + (size_t)bc * HW);
    float lmn = INFINITY, lmx = -INFINITY, lsum = 0.f;
    #pragma unroll
    for (int it = 0; it < 4; it++) {
        int idx = it * 256 + tid;
        if (idx < 784) {
            int i = idx / 14, j = (idx - i * 14) * 4;
            float o0 = qb, o1 = qb, o2v = qb, o3 = qb;
            #pragma unroll
            for (int r = 0; r < 3; r++) {
                const float* row = &tile[(i + r) * 68 + j + 3];
                float a0 = row[0];
                float4 mid = *(const float4*)&row[1];
                float a5 = row[5];
                float w0 = qw[3 * r], w1 = qw[3 * r + 1], w2 = qw[3 * r + 2];
                o0  += a0    * w0 + mid.x * w1 + mid.y * w2;
                o1  += mid.x * w0 + mid.y * w1 + mid.z * w2;
                o2v += mid.y * w0 + mid.z * w1 + mid.w * w2;
                o3  += mid.z * w0 + mid.w * w1 + a5    * w2;
            }
            po[idx] = make_float4(o0, o1, o2v, o3);
            lmn = fminf(lmn, fminf(fminf(o0, o1), fminf(o2v, o3)));
            lmx = fmaxf(lmx, fmaxf(fmaxf(o0, o1), fmaxf(o2v, o3)));
            lsum += (o0 + o1) + (o2v + o3);
        }
    }
    blk_red_minmax(lmn, lmx);
    float ls = blk_red_sum(lsum);
    if (tid == 0) { h1mn[bc] = lmn; h1mx[bc] = lmx; h1sm[bc] = ls; }
}

// all h1-derived scalars/coeffs, wave-parallel. Outputs sc[6..9,14,15], A2v/B2v.
__global__ __launch_bounds__(256) void k_stats1(const float* __restrict__ h1mn, const float* __restrict__ h1mx,
                                                const float* __restrict__ h1sm,
                                                const float* __restrict__ bn1w, const float* __restrict__ bn1b,
                                                float* sc,
                                                float* __restrict__ A2v, float* __restrict__ B2v) {
    int tid = threadIdx.x, lane = tid & 63, w = tid >> 6;
    __shared__ float bmn[32], bmx[32], sp[4], lP[256], lQ[256];
    #pragma unroll
    for (int i = 0; i < 8; i++) {
        int b = w * 8 + i;
        float4 m4 = *(const float4*)&h1mn[b * 256 + lane * 4];
        float4 x4 = *(const float4*)&h1mx[b * 256 + lane * 4];
        float mn = fminf(fminf(m4.x, m4.y), fminf(m4.z, m4.w));
        float mx = fmaxf(fmaxf(x4.x, x4.y), fmaxf(x4.z, x4.w));
        #pragma unroll
        for (int o = 32; o > 0; o >>= 1) { mn = fminf(mn, __shfl_down(mn, o)); mx = fmaxf(mx, __shfl_down(mx, o)); }
        if (lane == 0) { bmn[b] = mn; bmx[b] = mx; }
    }
    __syncthreads();
    if (tid == 0) {
        float sm = 0.f, sx = 0.f;
        for (int i = 0; i < 32; i++) { sm += bmn[i]; sx += bmx[i]; }
        float m = sm / 32.f, X = sx / 32.f;
        sp[0] = m; sp[1] = fmaxf((X - m) / 255.f, 1e-8f);
        sc[6] = sp[0]; sc[7] = sp[1];
        sc[14] = 1.f / sp[1];
        sc[15] = -sp[0] / sp[1];
    }
    __syncthreads();
    float mn1 = sp[0], s1 = sp[1];
    int c = tid;
    float mmax = 0.f, mmin = 0.f, sum = 0.f;
    #pragma unroll
    for (int ck = 0; ck < 16; ck++) {
        float c0n = h1mn[(2 * ck) * 256 + c], c1n = h1mn[(2 * ck + 1) * 256 + c];
        float c0x = h1mx[(2 * ck) * 256 + c], c1x = h1mx[(2 * ck + 1) * 256 + c];
        mmin += qz(fminf(c0n, c1n), mn1, s1);
        mmax += qz(fmaxf(c0x, c1x), mn1, s1);
        sum  += h1sm[(2 * ck) * 256 + c] + h1sm[(2 * ck + 1) * 256 + c];
    }
    mmin *= 0.0625f; mmax *= 0.0625f;
    float mean = sum / 100352.f;
    const float scale_fix = (float)(0.175 * (1.0 + sqrt(3.14159265358979323846 * log(4.0))) / sqrt(2.0 * log(6272.0)));
    float scale = 1.f / ((mmax - mmin) * scale_fix + 1e-5f);
    float ssn = scale, ssx = scale;
    blk_red_minmax_bcast(ssn, ssx);
    float wv = bn1w[c];
    float wmn = wv, wmx = wv;
    blk_red_minmax_bcast(wmn, wmx);
    float qs = qz(scale, ssn, fmaxf((ssx - ssn) / 255.f, 1e-8f));
    float qw = qz(wv, wmn, fmaxf((wmx - wmn) / 255.f, 1e-8f));
    float a1 = qs * qw;
    float be = bn1b[c] - mean * a1;
    float p1v = s1 * a1, q1v = mn1 * a1 + be;
    lP[c] = p1v; lQ[c] = q1v;
    __syncthreads();
    #pragma unroll
    for (int i = 0; i < 8; i++) {
        int b = w * 8 + i;
        float4 m4 = *(const float4*)&h1mn[b * 256 + lane * 4];
        float4 x4 = *(const float4*)&h1mx[b * 256 + lane * 4];
        float mn = INFINITY, mx = -INFINITY;
        #pragma unroll
        for (int j = 0; j < 4; j++) {
            int cc = lane * 4 + j;
            float kn = rintf(fminf(fmaxf(((&m4.x)[j] - mn1) / s1, 0.f), 255.f));
            float kx = rintf(fminf(fmaxf(((&x4.x)[j] - mn1) / s1, 0.f), 255.f));
            float hn = fmaxf(kn * lP[cc] + lQ[cc], 0.f);
            float hx = fmaxf(kx * lP[cc] + lQ[cc], 0.f);
            mn = fminf(mn, hn); mx = fmaxf(mx, hx);
        }
        #pragma unroll
        for (int o = 32; o > 0; o >>= 1) { mn = fminf(mn, __shfl_down(mn, o)); mx = fmaxf(mx, __shfl_down(mx, o)); }
        if (lane == 0) { bmn[b] = mn; bmx[b] = mx; }
    }
    __syncthreads();
    if (tid == 0) {
        float sm = 0.f, sx = 0.f;
        for (int i = 0; i < 32; i++) { sm += bmn[i]; sx += bmx[i]; }
        float m = sm / 32.f, X = sx / 32.f;
        sp[2] = m; sp[3] = fmaxf((X - m) / 255.f, 1e-8f);
        sc[8] = sp[2]; sc[9] = sp[3];
    }
    __syncthreads();
    A2v[c] = lP[c] / sp[3];
    B2v[c] = (lQ[c] - sp[2]) / sp[3];
}

// PASS 1: convert h1 -> offset i8 codes (cached to blob), MFMA, per-(b,co) stats only.
// blob layout: [(b*49+pt)*4096 + p*64 + dw] dwords (4 codes/dword), matching AsU rows.
__global__ __launch_bounds__(256) void k_gemm1(const float* __restrict__ h1, const char* __restrict__ wcodes,
                                               const float* __restrict__ Wsum, const float* __restrict__ sc,
                                               const float* __restrict__ A2v, const float* __restrict__ B2v,
                                               unsigned* __restrict__ blob, float* __restrict__ BpG,
                                               unsigned* o2mn, unsigned* o2mx, float* o2sum) {
    int b = blockIdx.y, pt = blockIdx.x, p0 = pt * 64;
    __shared__ unsigned AsU[64 * ASTR];    // 17.4 KB
    __shared__ float BpW[4][64];
    __shared__ float BpT[64];
    int tid = threadIdx.x, lane = tid & 63, w = tid >> 6;
    int col = lane & 15, quad = lane >> 4;
    float A1 = sc[14], B1 = sc[15];
    const float* colp = h1 + (size_t)b * SAMPLE + p0 + lane;
    unsigned base = lane * ASTR + 16 * w;
    float bp = 0.f;
    #pragma unroll 4
    for (int t2 = 0; t2 < 16; t2++) {
        int ci = 64 * w + 4 * t2;
        float v0 = colp[(size_t)ci * HW];
        float v1 = colp[(size_t)(ci + 1) * HW];
        float v2 = colp[(size_t)(ci + 2) * HW];
        float v3 = colp[(size_t)(ci + 3) * HW];
        float k0f = rintf(fminf(fmaxf(fmaf(v0, A1, B1), 0.f), 255.f));
        float k1f = rintf(fminf(fmaxf(fmaf(v1, A1, B1), 0.f), 255.f));
        float k2f = rintf(fminf(fmaxf(fmaf(v2, A1, B1), 0.f), 255.f));
        float k3f = rintf(fminf(fmaxf(fmaf(v3, A1, B1), 0.f), 255.f));
        float c0 = rintf(fminf(fmaxf(fmaf(k0f, A2v[ci],     B2v[ci]),     0.f), 255.f));
        float c1 = rintf(fminf(fmaxf(fmaf(k1f, A2v[ci + 1], B2v[ci + 1]), 0.f), 255.f));
        float c2 = rintf(fminf(fmaxf(fmaf(k2f, A2v[ci + 2], B2v[ci + 2]), 0.f), 255.f));
        float c3 = rintf(fminf(fmaxf(fmaf(k3f, A2v[ci + 3], B2v[ci + 3]), 0.f), 255.f));
        bp += (c0 + c1) + (c2 + c3);
        unsigned b0 = (unsigned)(((int)c0 - 128) & 0xFF);
        unsigned b1 = (unsigned)(((int)c1 - 128) & 0xFF);
        unsigned b2 = (unsigned)(((int)c2 - 128) & 0xFF);
        unsigned b3 = (unsigned)(((int)c3 - 128) & 0xFF);
        AsU[base + t2] = b0 | (b1 << 8) | (b2 << 16) | (b3 << 24);
    }
    BpW[w][lane] = bp;
    __syncthreads();
    // cache codes to global (coalesced via LDS)
    unsigned bbase = (unsigned)(b * 49 + pt) * 4096;
    #pragma unroll
    for (int i = 0; i < 16; i++) {
        int idx = i * 256 + tid;
        blob[bbase + idx] = AsU[(idx >> 6) * ASTR + (idx & 63)];
    }
    if (tid < 64) {
        float s = BpW[0][tid] + BpW[1][tid] + BpW[2][tid] + BpW[3][tid];
        BpT[tid] = s;
        BpG[(size_t)b * HW + p0 + tid] = s;
    }
    __syncthreads();
    const char* wb = wcodes + (size_t)(w * 64 + col) * 256 + quad * 16;
    i32x4 acc[4][4];
    #pragma unroll
    for (int i = 0; i < 4; i++)
        #pragma unroll
        for (int j = 0; j < 4; j++) acc[i][j] = (i32x4){0, 0, 0, 0};
    i32x4 bcur[4];
    #pragma unroll
    for (int nt = 0; nt < 4; nt++) bcur[nt] = *(const i32x4*)(wb + (size_t)nt * 4096);
    for (int step = 0; step < 4; step++) {
        i32x4 af[4];
        #pragma unroll
        for (int mt = 0; mt < 4; mt++)
            af[mt] = *(const i32x4*)&AsU[(size_t)(mt * 16 + col) * ASTR + step * 16 + quad * 4];
        i32x4 bnx[4];
        if (step < 3) {
            #pragma unroll
            for (int nt = 0; nt < 4; nt++) bnx[nt] = *(const i32x4*)(wb + (size_t)nt * 4096 + (step + 1) * 64);
        }
        #pragma unroll
        for (int mt = 0; mt < 4; mt++)
            #pragma unroll
            for (int nt = 0; nt < 4; nt++)
                acc[mt][nt] = __builtin_amdgcn_mfma_i32_16x16x64_i8(af[mt], bcur[nt], acc[mt][nt], 0, 0, 0);
        if (step < 3) {
            #pragma unroll
            for (int nt = 0; nt < 4; nt++) bcur[nt] = bnx[nt];
        }
    }
    float alpha = sc[11] * sc[9];
    float beta  = sc[11] * sc[8] + 128.f * alpha;
    float gamma = sc[10] * sc[9] + 128.f * alpha;
    float delta = 256.f * sc[10] * sc[8] - 4194304.f * alpha;
    float Wv[4];
    #pragma unroll
    for (int nt = 0; nt < 4; nt++) Wv[nt] = Wsum[w * 64 + nt * 16 + col];
    float snn[4], sxx[4], ssm[4];
    #pragma unroll
    for (int nt = 0; nt < 4; nt++) { snn[nt] = INFINITY; sxx[nt] = -INFINITY; ssm[nt] = 0.f; }
    #pragma unroll
    for (int mt = 0; mt < 4; mt++) {
        float bp4[4];
        #pragma unroll
        for (int r = 0; r < 4; r++) bp4[r] = BpT[mt * 16 + quad * 4 + r];
        #pragma unroll
        for (int nt = 0; nt < 4; nt++) {
            float wterm = beta * Wv[nt] + delta;
            #pragma unroll
            for (int r = 0; r < 4; r++) {
                float val = alpha * (float)acc[mt][nt][r] + gamma * bp4[r] + wterm;
                snn[nt] = fminf(snn[nt], val);
                sxx[nt] = fmaxf(sxx[nt], val);
                ssm[nt] += val;
            }
        }
    }
    #pragma unroll
    for (int nt = 0; nt < 4; nt++) {
        snn[nt] = fminf(snn[nt], __shfl_xor(snn[nt], 16));
        sxx[nt] = fmaxf(sxx[nt], __shfl_xor(sxx[nt], 16));
        ssm[nt] += __shfl_xor(ssm[nt], 16);
        snn[nt] = fminf(snn[nt], __shfl_xor(snn[nt], 32));
        sxx[nt] = fmaxf(sxx[nt], __shfl_xor(sxx[nt], 32));
        ssm[nt] += __shfl_xor(ssm[nt], 32);
    }
    if (lane < 16) {
        #pragma unroll
        for (int nt = 0; nt < 4; nt++) {
            int idx = b * 256 + w * 64 + nt * 16 + lane;
            atomicMin(&o2mn[idx], enc(snn[nt]));
            atomicMax(&o2mx[idx], enc(sxx[nt]));
            atomicAdd(&o2sum[idx], ssm[nt]);
        }
    }
}

// out2-derived scalars/coeffs, wave-parallel phase 1, unrolled loads.
__global__ __launch_bounds__(256) void k_stats2(const unsigned* __restrict__ o2mnU, const unsigned* __restrict__ o2mxU,
                                                const float* __restrict__ o2sm,
                                                const float* __restrict__ bn2w, const float* __restrict__ bn2b,
                                                float* sc, float* __restrict__ P2, float* __restrict__ Q2) {
    int tid = threadIdx.x, lane = tid & 63, w = tid >> 6;
    __shared__ float bmn[32], bmx[32], sp[2];
    #pragma unroll
    for (int i = 0; i < 8; i++) {
        int b = w * 8 + i;
        uint4 um = *(const uint4*)&o2mnU[b * 256 + lane * 4];
        uint4 ux = *(const uint4*)&o2mxU[b * 256 + lane * 4];
        float mn = fminf(fminf(dec(um.x), dec(um.y)), fminf(dec(um.z), dec(um.w)));
        float mx = fmaxf(fmaxf(dec(ux.x), dec(ux.y)), fmaxf(dec(ux.z), dec(ux.w)));
        #pragma unroll
        for (int o = 32; o > 0; o >>= 1) { mn = fminf(mn, __shfl_down(mn, o)); mx = fmaxf(mx, __shfl_down(mx, o)); }
        if (lane == 0) { bmn[b] = mn; bmx[b] = mx; }
    }
    __syncthreads();
    if (tid == 0) {
        float sm = 0.f, sx = 0.f;
        for (int i = 0; i < 32; i++) { sm += bmn[i]; sx += bmx[i]; }
        float m = sm / 32.f, X = sx / 32.f;
        sp[0] = m; sp[1] = fmaxf((X - m) / 255.f, 1e-8f);
        sc[12] = sp[0]; sc[13] = sp[1];
    }
    __syncthreads();
    float mno = sp[0], so = sp[1];
    int c = tid;
    float mmax = 0.f, mmin = 0.f, sum = 0.f;
    #pragma unroll
    for (int ck = 0; ck < 16; ck++) {
        float c0n = dec(o2mnU[(2 * ck) * 256 + c]), c1n = dec(o2mnU[(2 * ck + 1) * 256 + c]);
        float c0x = dec(o2mxU[(2 * ck) * 256 + c]), c1x = dec(o2mxU[(2 * ck + 1) * 256 + c]);
        mmin += qz(fminf(c0n, c1n), mno, so);
        mmax += qz(fmaxf(c0x, c1x), mno, so);
        sum  += o2sm[(2 * ck) * 256 + c] + o2sm[(2 * ck + 1) * 256 + c];
    }
    mmin *= 0.0625f; mmax *= 0.0625f;
    float mean = sum / 100352.f;
    const float scale_fix = (float)(0.175 * (1.0 + sqrt(3.14159265358979323846 * log(4.0))) / sqrt(2.0 * log(6272.0)));
    float scale = 1.f / ((mmax - mmin) * scale_fix + 1e-5f);
    float ssn = scale, ssx = scale;
    blk_red_minmax_bcast(ssn, ssx);
    float wv = bn2w[c];
    float wmn = wv, wmx = wv;
    blk_red_minmax_bcast(wmn, wmx);
    float qs = qz(scale, ssn, fmaxf((ssx - ssn) / 255.f, 1e-8f));
    float qw = qz(wv, wmn, fmaxf((wmx - wmn) / 255.f, 1e-8f));
    float a2 = qs * qw;
    float be = bn2b[c] - mean * a2;
    P2[c] = so * a2; Q2[c] = mno * a2 + be;
}

// PASS 2: reload codes from blob, MFMA, fused BN2+quantize+relu epilogue with
// in-LDS 16x256 transpose; writes final NCHW output. Replaces o2 store + k_apply.
__global__ __launch_bounds__(256) void k_gemm2(const unsigned* __restrict__ blob, const char* __restrict__ wcodes,
                                               const float* __restrict__ Wsum, const float* __restrict__ BpG,
                                               const float* __restrict__ sc,
                                               const float* __restrict__ P2, const float* __restrict__ Q2,
                                               float* __restrict__ out) {
    int b = blockIdx.y, pt = blockIdx.x, p0 = pt * 64;
    __shared__ unsigned smem[64 * ASTR];       // 17.4 KB: AsU during MFMA, then 16x260 f32 transpose buf
    float* sT = (float*)smem;
    int tid = threadIdx.x, lane = tid & 63, w = tid >> 6;
    int col = lane & 15, quad = lane >> 4;
    const unsigned* ab = blob + (size_t)((unsigned)(b * 49 + pt)) * 4096;
    #pragma unroll
    for (int i = 0; i < 16; i++) {
        int idx = i * 256 + tid;
        smem[(idx >> 6) * ASTR + (idx & 63)] = ab[idx];
    }
    __syncthreads();
    const char* wb = wcodes + (size_t)(w * 64 + col) * 256 + quad * 16;
    i32x4 acc[4][4];
    #pragma unroll
    for (int i = 0; i < 4; i++)
        #pragma unroll
        for (int j = 0; j < 4; j++) acc[i][j] = (i32x4){0, 0, 0, 0};
    i32x4 bcur[4];
    #pragma unroll
    for (int nt = 0; nt < 4; nt++) bcur[nt] = *(const i32x4*)(wb + (size_t)nt * 4096);
    for (int step = 0; step < 4; step++) {
        i32x4 af[4];
        #pragma unroll
        for (int mt = 0; mt < 4; mt++)
            af[mt] = *(const i32x4*)&smem[(size_t)(mt * 16 + col) * ASTR + step * 16 + quad * 4];
        i32x4 bnx[4];
        if (step < 3) {
            #pragma unroll
            for (int nt = 0; nt < 4; nt++) bnx[nt] = *(const i32x4*)(wb + (size_t)nt * 4096 + (step + 1) * 64);
        }
        #pragma unroll
        for (int mt = 0; mt < 4; mt++)
            #pragma unroll
            for (int nt = 0; nt < 4; nt++)
                acc[mt][nt] = __builtin_amdgcn_mfma_i32_16x16x64_i8(af[mt], bcur[nt], acc[mt][nt], 0, 0, 0);
        if (step < 3) {
            #pragma unroll
            for (int nt = 0; nt < 4; nt++) bcur[nt] = bnx[nt];
        }
    }
    float alpha = sc[11] * sc[9];
    float beta  = sc[11] * sc[8] + 128.f * alpha;
    float gamma = sc[10] * sc[9] + 128.f * alpha;
    float delta = 256.f * sc[10] * sc[8] - 4194304.f * alpha;
    float mno = sc[12], so = sc[13];
    float Wv[4], bpv[4][4];
    #pragma unroll
    for (int nt = 0; nt < 4; nt++) Wv[nt] = Wsum[w * 64 + nt * 16 + col];
    #pragma unroll
    for (int mt = 0; mt < 4; mt++)
        #pragma unroll
        for (int r = 0; r < 4; r++) bpv[mt][r] = BpG[(size_t)b * HW + p0 + mt * 16 + quad * 4 + r];
    int co_g = tid >> 4, pl = tid & 15;
    #pragma unroll
    for (int mt = 0; mt < 4; mt++) {
        __syncthreads();        // previous chunk's reads (or MFMA's AsU reads) done
        #pragma unroll
        for (int nt = 0; nt < 4; nt++) {
            float wterm = beta * Wv[nt] + delta;
            #pragma unroll
            for (int r = 0; r < 4; r++) {
                float val = alpha * (float)acc[mt][nt][r] + gamma * bpv[mt][r] + wterm;
                sT[(quad * 4 + r) * 260 + w * 64 + nt * 16 + col] = val;
            }
        }
        __syncthreads();
        float* orow = out + (size_t)b * SAMPLE + (size_t)0 * HW + p0 + mt * 16 + pl;
        #pragma unroll
        for (int ii = 0; ii < 16; ii++) {
            int co = ii * 16 + co_g;
            float val = sT[pl * 260 + co];
            float k2 = rintf(fminf(fmaxf((val - mno) / so, 0.f), 255.f));
            float ov = fmaxf(k2 * P2[co] + Q2[co], 0.f);
            orow[(size_t)co * HW] = ov;
        }
    }
}

// ---------- launch ----------

extern "C" void kernel_launch(void* const* d_in, const int* in_sizes, int n_in,
                              void* d_out, int out_size, void* d_ws, size_t ws_size,
                              hipStream_t stream) {
    (void)in_sizes; (void)n_in; (void)out_size; (void)ws_size;
    const float* x    = (const float*)d_in[0];
    const float* dww  = (const float*)d_in[1];
    const float* dwb  = (const float*)d_in[2];
    const float* bn1w = (const float*)d_in[3];
    const float* bn1b = (const float*)d_in[4];
    const float* pww  = (const float*)d_in[5];
    const float* bn2w = (const float*)d_in[6];
    const float* bn2b = (const float*)d_in[7];

    float* h1   = (float*)d_ws;                  // TOT  [b][ci][p]
    unsigned* blob = (unsigned*)(h1 + TOT);      // TOT/4 dwords (i8 codes, AsU row order)
    float* after = (float*)(blob + TOT / 4);
    char* wcodes = (char*)after;                 // 65536 bytes = 16384 floats
    float* Wsum  = after + 16384;                // 256
    float* BpG   = Wsum + 256;                   // 32*3136 = 100352
    float* sc    = BpG + 100352;                 // 32
    unsigned* xsl   = (unsigned*)(sc + 32);      // 64
    unsigned* pwsl  = xsl + 64;                  // 2 (padded 64)
    unsigned* o2mnU = pwsl + 64;                 // 8192
    unsigned* o2mxU = o2mnU + 8192;              // 8192
    float* o2sm = (float*)(o2mxU + 8192);        // 8192
    float* h1mn = o2sm + 8192;                   // 8192
    float* h1mx = h1mn + 8192;                   // 8192
    float* h1sm = h1mx + 8192;                   // 8192
    float* P2 = h1sm + 8192; float* Q2 = P2 + 256;
    float* A2v = Q2 + 256;   float* B2v = A2v + 256;

    k_init<<<32, 256, 0, stream>>>(xsl, pwsl, o2mnU, o2mxU, o2sm);
    k_front<<<576, 256, 0, stream>>>((const float4*)x, (const float4*)pww, xsl, pwsl);
    k_fin1<<<1, 256, 0, stream>>>(dww, dwb, xsl, pwsl, sc);
    k_qw<<<256, 256, 0, stream>>>(pww, sc, wcodes, Wsum);
    k_dwconv<<<NB * NCH, 256, 0, stream>>>((const float4*)x, dww, dwb, h1, sc, h1mn, h1mx, h1sm);
    k_stats1<<<1, 256, 0, stream>>>(h1mn, h1mx, h1sm, bn1w, bn1b, sc, A2v, B2v);
    k_gemm1<<<dim3(49, 32), 256, 0, stream>>>(h1, wcodes, Wsum, sc, A2v, B2v, blob, BpG, o2mnU, o2mxU, o2sm);
    k_stats2<<<1, 256, 0, stream>>>(o2mnU, o2mxU, o2sm, bn2w, bn2b, sc, P2, Q2);
    k_gemm2<<<dim3(49, 32), 256, 0, stream>>>(blob, wcodes, Wsum, BpG, sc, P2, Q2, (float*)d_out);
}